// Round 1
// 123.460 us; speedup vs baseline: 1.0745x; 1.0745x over previous
//
#include <hip/hip_runtime.h>

#define N_WORDS   16384
#define L_CHARS   16
#define CHAR_SIZE 128
#define C_EMB     64
#define CONV_L    256
#define KERNEL_K  3
#define D_EMB     300
#define OUT_STRIDE (CONV_L + D_EMB)   // 556
#define CH_Q      64                  // channels per quarter-slice
#define SLICE_H   (CHAR_SIZE * KERNEL_K * CH_Q)   // 24576 halves = 48 KB

typedef _Float16 half8 __attribute__((ext_vector_type(8)));

static __device__ __forceinline__ half8 h8max(half8 a, half8 b) {
#if __has_builtin(__builtin_elementwise_max)
    return __builtin_elementwise_max(a, b);
#else
    half8 r;
    #pragma unroll
    for (int i = 0; i < 8; ++i) r[i] = a[i] > b[i] ? a[i] : b[i];
    return r;
#endif
}

// ---------------------------------------------------------------------------
// R3 Kernel A: fused transpose+fold (replaces transpose_w + build_table;
// saves one launch + graph gap). One block per output channel o.
//   Th[q][c][k][oi] = (half) sum_i emb[c][i] * w[o][i][k],  o = q*64+oi
// emb staged in LDS padded to 65 floats/row: lane stride 65 -> 2-way bank
// aliasing only (free per m136). w-row (768 B) staged in LDS; k is
// wave-uniform (tid>>7, 128 | 64-lane waves) so ws[i*3+k] is an LDS
// broadcast. Same fp32 accumulation order as before -> bit-identical Th.
__global__ __launch_bounds__(384)
void build_table_fused(const float* __restrict__ emb,
                       const float* __restrict__ w,
                       _Float16* __restrict__ Th) {
    __shared__ float es[CHAR_SIZE * 65];          // 33.3 KB
    __shared__ float ws[C_EMB * KERNEL_K];        // 768 B
    const int o = blockIdx.x;

    for (int idx = threadIdx.x; idx < CHAR_SIZE * C_EMB; idx += 384) {
        int c = idx >> 6, i = idx & 63;
        es[c * 65 + i] = emb[idx];
    }
    if (threadIdx.x < C_EMB * KERNEL_K)
        ws[threadIdx.x] = w[o * (C_EMB * KERNEL_K) + threadIdx.x];
    __syncthreads();

    const int k = threadIdx.x >> 7;    // 0..2, uniform per 64-lane wave
    const int c = threadIdx.x & 127;
    float s = 0.f;
    #pragma unroll
    for (int i = 0; i < C_EMB; ++i)
        s += es[c * 65 + i] * ws[i * KERNEL_K + k];

    Th[(o >> 6) * SLICE_H + c * (KERNEL_K * CH_Q) + k * CH_Q + (o & 63)]
        = (_Float16)s;
}

// ---------------------------------------------------------------------------
// Kernel B (fused main).
// Blocks [0, WB): word-embedding gather, 2x-unrolled so two independent
//   HBM gather chains are in flight (halves the dependent-latency chain).
// Blocks [WB, WB+CB): char conv/maxpool. R3: CB = 512 blocks x 128 words
//   (4 passes) -- halves the 48 KB-slice staging redundancy (48 -> 24 MB of
//   L2 reads) and makes the grid exactly 768 = 3 blocks/CU (the LDS
//   occupancy limit), no scheduling remainder. q = cb&3 stays constant per
//   XCD (stride-8 round-robin), so each XCD L2 serves a single 48 KB slice.
//   Next pass's X row is software-prefetched (static regs, unrolled).
__global__ __launch_bounds__(256, 3)
void main_kernel(const int* __restrict__ X,
                 const int* __restrict__ Xw,
                 const _Float16* __restrict__ Th,
                 const float* __restrict__ conv_b,
                 const float* __restrict__ word_emb,
                 float* __restrict__ out,
                 int word_blocks) {
    __shared__ __align__(16) _Float16 Ts[SLICE_H];   // 48 KB

    const int lane = threadIdx.x & 63;
    const int wv   = threadIdx.x >> 6;

    if ((int)blockIdx.x < word_blocks) {
        const int wavesTotal = word_blocks * 4;          // 1024
        const int waveId = blockIdx.x * 4 + wv;
        // 16384/1024 = 16 iterations -> 8 unroll-2 steps; n2 always valid.
        for (int n = waveId; n < N_WORDS; n += 2 * wavesTotal) {
            const int n2 = n + wavesTotal;
            int w0 = Xw[n];
            int w1 = Xw[n2];
            const float4* s0 = (const float4*)(word_emb + (size_t)w0 * D_EMB);
            const float4* s1 = (const float4*)(word_emb + (size_t)w1 * D_EMB);
            const bool tail = lane < (D_EMB / 4 - 64);   // 11 lanes
            float4 a0 = s0[lane], a1 = s1[lane];
            float4 b0 = {}, b1 = {};
            if (tail) { b0 = s0[64 + lane]; b1 = s1[64 + lane]; }
            float4* d0 = (float4*)(out + (size_t)n  * OUT_STRIDE + CONV_L);
            float4* d1 = (float4*)(out + (size_t)n2 * OUT_STRIDE + CONV_L);
            d0[lane] = a0;
            if (tail) d0[64 + lane] = b0;
            d1[lane] = a1;
            if (tail) d1[64 + lane] = b1;
        }
        return;
    }

    const int cb   = (int)blockIdx.x - word_blocks;   // 0..511
    const int q    = cb & 3;                          // channel quarter
    const int wgrp = cb >> 2;                         // word group, 0..127

    // ---- stage the 48 KB slice (fully coalesced contiguous read) ----
    {
        const float4* src = (const float4*)(Th + q * SLICE_H);
        float4* dst = (float4*)Ts;
        #pragma unroll
        for (int i = 0; i < 12; ++i)
            dst[threadIdx.x + i * 256] = src[threadIdx.x + i * 256];
    }
    __syncthreads();

    const int g  = lane >> 3;   // word within the wave's 8
    const int l8 = lane & 7;    // owns channels q*64 + l8*8 .. +8

    float bias[8];
    {
        const float4* bp = (const float4*)(conv_b + q * CH_Q + l8 * 8);
        float4 b0 = bp[0], b1 = bp[1];
        bias[0]=b0.x; bias[1]=b0.y; bias[2]=b0.z; bias[3]=b0.w;
        bias[4]=b1.x; bias[5]=b1.y; bias[6]=b1.z; bias[7]=b1.w;
    }

    // prefetch pass-0 X row (8 lanes share the 64 B row; L1 broadcast)
    int4 c0, c1, c2, c3;
    {
        const int n0 = wgrp * 128 + wv * 8 + g;
        const int4* xr = (const int4*)(X + n0 * L_CHARS);
        c0 = xr[0]; c1 = xr[1]; c2 = xr[2]; c3 = xr[3];
    }

    #pragma unroll
    for (int pass = 0; pass < 4; ++pass) {
        // issue next pass's X loads before the LDS-bound j-loop
        int4 p0 = c0, p1 = c1, p2 = c2, p3 = c3;
        if (pass < 3) {
            const int n1 = wgrp * 128 + (pass + 1) * 32 + wv * 8 + g;
            const int4* xr = (const int4*)(X + n1 * L_CHARS);
            p0 = xr[0]; p1 = xr[1]; p2 = xr[2]; p3 = xr[3];
        }

        const int n = wgrp * 128 + pass * 32 + wv * 8 + g;
        int cs[16] = {c0.x, c0.y, c0.z, c0.w,
                      c1.x, c1.y, c1.z, c1.w,
                      c2.x, c2.y, c2.z, c2.w,
                      c3.x, c3.y, c3.z, c3.w};

        half8 a0 = (half8)(_Float16)0.f;
        half8 a1 = (half8)(_Float16)0.f;
        half8 m  = (half8)(_Float16)(-65504.f);

        #pragma unroll
        for (int j = 0; j < L_CHARS; ++j) {
            const _Float16* row = Ts + cs[j] * (KERNEL_K * CH_Q) + l8 * 8;
            half8 t0 = *(const half8*)(row);            // k=0
            half8 t1 = *(const half8*)(row + CH_Q);     // k=1
            half8 t2 = *(const half8*)(row + 2*CH_Q);   // k=2
            half8 yj = a0 + t2;          // y[j] complete
            m  = h8max(m, yj);
            a0 = a1 + t1;                // partial y[j+1]
            a1 = t0;                     // partial y[j+2]
        }
        m = h8max(m, a0);   // y[16]
        m = h8max(m, a1);   // y[17]

        float r[8];
        #pragma unroll
        for (int e = 0; e < 8; ++e)
            r[e] = fmaxf((float)m[e] + bias[e], 0.f);
        float4* dst = (float4*)(out + (size_t)n * OUT_STRIDE + q * CH_Q + l8 * 8);
        dst[0] = make_float4(r[0], r[1], r[2], r[3]);
        dst[1] = make_float4(r[4], r[5], r[6], r[7]);

        c0 = p0; c1 = p1; c2 = p2; c3 = p3;
    }
}

extern "C" void kernel_launch(void* const* d_in, const int* in_sizes, int n_in,
                              void* d_out, int out_size, void* d_ws, size_t ws_size,
                              hipStream_t stream) {
    const int*   X    = (const int*)d_in[0];
    const int*   Xw   = (const int*)d_in[1];
    const float* emb  = (const float*)d_in[2];
    const float* w    = (const float*)d_in[3];
    const float* b    = (const float*)d_in[4];
    const float* we   = (const float*)d_in[5];
    float* out = (float*)d_out;

    // ws layout: Th (fp16, 196608 B) only -- Wt eliminated by fusion
    _Float16* Th = (_Float16*)d_ws;

    build_table_fused<<<CONV_L, 384, 0, stream>>>(emb, w, Th);

    const int WB = 256;    // word-gather blocks
    const int CB = 512;    // char blocks: 4 quarters x 128 word-groups
    main_kernel<<<WB + CB, 256, 0, stream>>>(X, Xw, Th, b, we, out, WB);
}